// Round 5
// baseline (668.870 us; speedup 1.0000x reference)
//
#include <hip/hip_runtime.h>
#include <hip/hip_bf16.h>

#define F 128

typedef unsigned int uint;
typedef unsigned short ushort;
typedef __attribute__((ext_vector_type(8))) short short8;   // 8 bf16
typedef __attribute__((ext_vector_type(4))) float f32x4;

__device__ inline ushort f2bf(float f) {
    uint u = __float_as_uint(f);
    u += 0x7FFF + ((u >> 16) & 1);   // round-to-nearest-even
    return (ushort)(u >> 16);
}
__device__ inline float2 bf2f(uint u) {
    return make_float2(__uint_as_float(u << 16), __uint_as_float(u & 0xFFFF0000u));
}

// ---------------- CSR build ----------------
__global__ __launch_bounds__(256) void rank_kernel(const int* __restrict__ dst,
                                                   int* __restrict__ cnt,
                                                   ushort* __restrict__ rel, int E) {
    int e = blockIdx.x * 256 + threadIdx.x;
    if (e < E) rel[e] = (ushort)atomicAdd(&cnt[dst[e]], 1);
}

__global__ __launch_bounds__(256) void scan_block(const int* __restrict__ cnt,
                                                  int* __restrict__ off,
                                                  int* __restrict__ bsum, int N) {
    __shared__ int t[256];
    int i = blockIdx.x * 256 + threadIdx.x;
    int v = (i < N) ? cnt[i] : 0;
    t[threadIdx.x] = v;
    __syncthreads();
    for (int o = 1; o < 256; o <<= 1) {
        int x = (threadIdx.x >= o) ? t[threadIdx.x - o] : 0;
        __syncthreads();
        t[threadIdx.x] += x;
        __syncthreads();
    }
    if (i < N) off[i] = t[threadIdx.x] - v;
    if (threadIdx.x == 255) bsum[blockIdx.x] = t[255];
}

__global__ __launch_bounds__(512) void scan_sums(int* __restrict__ bsum, int nb) {
    __shared__ int t[512];
    int v = (threadIdx.x < nb) ? bsum[threadIdx.x] : 0;
    t[threadIdx.x] = v;
    __syncthreads();
    for (int o = 1; o < 512; o <<= 1) {
        int x = (threadIdx.x >= o) ? t[threadIdx.x - o] : 0;
        __syncthreads();
        t[threadIdx.x] += x;
        __syncthreads();
    }
    if (threadIdx.x < nb) bsum[threadIdx.x] = t[threadIdx.x] - v;
}

__global__ __launch_bounds__(256) void scan_add_rdeg(int* __restrict__ off,
                                                     const int* __restrict__ bsum,
                                                     const int* __restrict__ cnt,
                                                     float* __restrict__ rdeg, int N) {
    int i = blockIdx.x * 256 + threadIdx.x;
    if (i >= N) return;
    off[i] += bsum[blockIdx.x];
    rdeg[i] = 1.0f / fmaxf((float)cnt[i], 1.0f);
}

__global__ __launch_bounds__(256) void fill_kernel(const int* __restrict__ src,
                                                   const int* __restrict__ dst,
                                                   const int* __restrict__ off,
                                                   const ushort* __restrict__ rel,
                                                   int* __restrict__ srcS, int E) {
    int e = blockIdx.x * 256 + threadIdx.x;
    if (e >= E) return;
    srcS[off[dst[e]] + (int)rel[e]] = src[e];
}

// ---------------- fused prep: cast x -> bf16 rows, plus weight cast + FRAG-MAJOR swizzle --
__global__ __launch_bounds__(256) void prep_kernel(const float* __restrict__ x,
                                                   const float* __restrict__ W0,
                                                   const float* __restrict__ W1,
                                                   const float* __restrict__ W2,
                                                   const float* __restrict__ W3,
                                                   uint* __restrict__ xb,
                                                   ushort* __restrict__ Wt, int NF4) {
    int i = blockIdx.x * 256 + threadIdx.x;
    if (i < NF4) {
        float4 v = ((const float4*)x)[i];
        uint ua = (uint)f2bf(v.x) | ((uint)f2bf(v.y) << 16);
        uint ub = (uint)f2bf(v.z) | ((uint)f2bf(v.w) << 16);
        ((uint2*)xb)[i] = make_uint2(ua, ub);
    } else {
        int idx = i - NF4;
        if (idx >= 4 * 16384) return;
        int j    = idx & 7;
        int lane = (idx >> 3) & 63;
        int t    = (idx >> 9) & 7;
        int kk   = (idx >> 12) & 3;
        int mat  = idx >> 14;
        int n = 16 * t + (lane & 15);
        int k = 32 * kk + 8 * (lane >> 4) + j;
        const float* W = (mat == 0) ? W0 : (mat == 1) ? W1 : (mat == 2) ? W2 : W3;
        Wt[idx] = f2bf(W[k * 128 + n]);
    }
}

// ---------------- aggregate: half-row per XCD-parity group ----------------
// XCDs 0-3 (blockIdx&7 < 4) process bytes [0,128) of every row; XCDs 4-7 bytes [128,256).
// Concurrent footprint per XCD = 12.8 MB (vs 25.6) -> higher L2 hit on random src rows.
// Wave = 1 node; per VMEM instr: 2 edges x 32 lanes x 4B = two 128B segments.
// Indices stay wave-uniform scalar loads; lane-half picks its edge via cndmask.
__global__ __launch_bounds__(256) void agg_gather_h(const uint* __restrict__ hb,
                                                    const int* __restrict__ off,
                                                    const int* __restrict__ srcS,
                                                    const float* __restrict__ rdeg,
                                                    uint* __restrict__ msgb, int N, int E) {
    int g = blockIdx.x;
    int xcd = g & 7;
    int half = xcd >> 2;                      // 0: features [0,64), 1: [64,128)
    int nb = (g >> 3) * 4 + (xcd & 3);        // within-half block id
    int node = nb * 4 + (threadIdx.x >> 6);
    int lane = threadIdx.x & 63;
    int l32 = lane & 31;
    int eh = lane >> 5;                       // lane-half: accumulates even/odd edge slots
    if (node >= N) return;
    int hofs = half * 32 + l32;               // uint offset within a 64-uint row
    int p = off[node];
    int pe = (node == N - 1) ? E : off[node + 1];
    float2 acc = make_float2(0.f, 0.f);
    int d = 0, last = 0;
    if (p < pe) {
        int deg = pe - p;
        last = pe - 1;
        for (; p < pe; p += 8) {
            int s0 = srcS[min(p + 0, last)], s1 = srcS[min(p + 1, last)];
            int s2 = srcS[min(p + 2, last)], s3 = srcS[min(p + 3, last)];
            int s4 = srcS[min(p + 4, last)], s5 = srcS[min(p + 5, last)];
            int s6 = srcS[min(p + 6, last)], s7 = srcS[min(p + 7, last)];
            int a0 = eh ? s1 : s0;
            int a1 = eh ? s3 : s2;
            int a2 = eh ? s5 : s4;
            int a3 = eh ? s7 : s6;
            float2 f0 = bf2f(hb[(size_t)a0 * 64 + hofs]);
            float2 f1 = bf2f(hb[(size_t)a1 * 64 + hofs]);
            float2 f2 = bf2f(hb[(size_t)a2 * 64 + hofs]);
            float2 f3 = bf2f(hb[(size_t)a3 * 64 + hofs]);
            acc.x += (f0.x + f1.x) + (f2.x + f3.x);
            acc.y += (f0.y + f1.y) + (f2.y + f3.y);
        }
        d = (8 - (deg & 7)) & 7;              // duplicate adds of row[last] (final iter only)
    }
    // combine even/odd edge-slot partials across the two lane-halves
    acc.x += __shfl_xor(acc.x, 32);
    acc.y += __shfl_xor(acc.y, 32);
    if (eh == 0) {
        if (d) {
            float2 fl = bf2f(hb[(size_t)srcS[last] * 64 + hofs]);
            float fd = (float)d;
            acc.x -= fd * fl.x;
            acc.y -= fd * fl.y;
        }
        float rd = rdeg[node];
        msgb[(size_t)node * 64 + hofs] =
            (uint)f2bf(acc.x * rd) | ((uint)f2bf(acc.y * rd) << 16);
    }
}

// ---------------- SAGE layer via MFMA (frag-major weights) ----------------
__global__ __launch_bounds__(256) void sage_mfma(const uint* __restrict__ hb,
                                                 const uint* __restrict__ mb,
                                                 const uint* __restrict__ Wt,  // frag-major
                                                 const float* __restrict__ bias,
                                                 ushort* __restrict__ outb, int N) {
    int wave = threadIdx.x >> 6, lane = threadIdx.x & 63;
    int m = lane & 15, q = lane >> 4;
    int r0 = blockIdx.x * 64 + wave * 16;
    int arow = r0 + m;
    if (arow >= N) arow = N - 1;

    f32x4 acc[8];
#pragma unroll
    for (int t = 0; t < 8; t++) acc[t] = (f32x4){0.f, 0.f, 0.f, 0.f};

    const uint* hrow = hb + (size_t)arow * 64;
    const uint* mrow = mb + (size_t)arow * 64;
#pragma unroll
    for (int sel = 0; sel < 2; sel++) {
        const uint* arowp = sel ? mrow : hrow;
        const uint* wsel = Wt + sel * 8192;
#pragma unroll
        for (int kk = 0; kk < 4; kk++) {
            int ko = kk * 16 + q * 4;
            short8 a = *(const short8*)(arowp + ko);
#pragma unroll
            for (int t = 0; t < 8; t++) {
                short8 b = *(const short8*)(wsel + (size_t)((kk * 8 + t) * 64 + lane) * 4);
                acc[t] = __builtin_amdgcn_mfma_f32_16x16x32_bf16(a, b, acc[t], 0, 0, 0);
            }
        }
    }

#pragma unroll
    for (int t = 0; t < 8; t++) {
        float bs = bias[16 * t + m];
#pragma unroll
        for (int r = 0; r < 4; r++) {
            int orow = r0 + q * 4 + r;
            if (orow < N) outb[(size_t)orow * 128 + 16 * t + m] = f2bf(acc[t][r] + bs);
        }
    }
}

// ---------------- edge score via MFMA, half-feature per pass ----------------
// PH=0: dot over features [0,64), write partial sc (no minmax).
// PH=1: dot over features [64,128), sc += partial, min/max on the total.
// Per-pass gather footprint = 12.8 MB -> higher L2 hit.
template <int PH>
__global__ __launch_bounds__(256) void edge_score_h(const uint* __restrict__ hb,
                                                    const int* __restrict__ off,
                                                    const int* __restrict__ srcS,
                                                    float* __restrict__ sc,
                                                    float2* __restrict__ pmm, int N, int E) {
    int node = blockIdx.x * 4 + (threadIdx.x >> 6);
    int lane = threadIdx.x & 63;
    int m = lane & 15, q = lane >> 4;
    float lmin = INFINITY, lmax = -INFINITY;

    if (node < N) {
        int p = off[node];
        int pe = (node == N - 1) ? E : off[node + 1];
        if (p < pe) {
            const uint* nrow = hb + (size_t)node * 64;
            short8 bfr[2];
#pragma unroll
            for (int kk = 0; kk < 2; kk++)
                bfr[kk] = *(const short8*)(nrow + (PH * 2 + kk) * 16 + q * 4);

            for (; p < pe; p += 16) {
                int idx = p + m;
                if (idx >= pe) idx = pe - 1;              // clamp: dup rows, stores masked
                const uint* arow = hb + (size_t)srcS[idx] * 64;
                f32x4 acc = (f32x4){0.f, 0.f, 0.f, 0.f};
#pragma unroll
                for (int kk = 0; kk < 2; kk++) {
                    short8 a = *(const short8*)(arow + (PH * 2 + kk) * 16 + q * 4);
                    acc = __builtin_amdgcn_mfma_f32_16x16x32_bf16(a, bfr[kk], acc, 0, 0, 0);
                }
                if (m == 0) {
                    if (p + 16 <= pe) {
                        if (PH == 0) {
                            *(float4*)(sc + p + q * 4) =
                                make_float4(acc[0], acc[1], acc[2], acc[3]);
                        } else {
                            float4 o = *(const float4*)(sc + p + q * 4);
                            o.x += acc[0]; o.y += acc[1]; o.z += acc[2]; o.w += acc[3];
                            *(float4*)(sc + p + q * 4) = o;
                            float mn = fminf(fminf(o.x, o.y), fminf(o.z, o.w));
                            float mx = fmaxf(fmaxf(o.x, o.y), fmaxf(o.z, o.w));
                            lmin = fminf(lmin, mn);
                            lmax = fmaxf(lmax, mx);
                        }
                    } else {
#pragma unroll
                        for (int r = 0; r < 4; r++) {
                            int e = p + q * 4 + r;
                            if (e < pe) {
                                if (PH == 0) {
                                    sc[e] = acc[r];
                                } else {
                                    float o = sc[e] + acc[r];
                                    sc[e] = o;
                                    lmin = fminf(lmin, o);
                                    lmax = fmaxf(lmax, o);
                                }
                            }
                        }
                    }
                }
            }
        }
    }

    if (PH == 1) {
#pragma unroll
        for (int o = 1; o <= 32; o <<= 1) {
            lmin = fminf(lmin, __shfl_xor(lmin, o));
            lmax = fmaxf(lmax, __shfl_xor(lmax, o));
        }
        __shared__ float smin[4], smax[4];
        int wv = threadIdx.x >> 6;
        if (lane == 0) { smin[wv] = lmin; smax[wv] = lmax; }
        __syncthreads();
        if (threadIdx.x == 0) {
            float mA = fminf(fminf(smin[0], smin[1]), fminf(smin[2], smin[3]));
            float MA = fmaxf(fmaxf(smax[0], smax[1]), fmaxf(smax[2], smax[3]));
            pmm[blockIdx.x] = make_float2(mA, MA);
        }
    }
}

__global__ __launch_bounds__(1024) void minmax_final(const float2* __restrict__ pmm,
                                                     float* __restrict__ mmf, int nb) {
    float vmin = INFINITY, vmax = -INFINITY;
    for (int i = threadIdx.x; i < nb; i += 1024) {
        float2 v = pmm[i];
        vmin = fminf(vmin, v.x);
        vmax = fmaxf(vmax, v.y);
    }
#pragma unroll
    for (int o = 1; o <= 32; o <<= 1) {
        vmin = fminf(vmin, __shfl_xor(vmin, o));
        vmax = fmaxf(vmax, __shfl_xor(vmax, o));
    }
    __shared__ float smin[16], smax[16];
    int lane = threadIdx.x & 63, wv = threadIdx.x >> 6;
    if (lane == 0) { smin[wv] = vmin; smax[wv] = vmax; }
    __syncthreads();
    if (threadIdx.x == 0) {
        float m = smin[0], M = smax[0];
        for (int w = 1; w < 16; w++) { m = fminf(m, smin[w]); M = fmaxf(M, smax[w]); }
        mmf[0] = m;
        mmf[1] = M;
    }
}

// out[e] = (sc[off[dst[e]] + rel[e]] - mn) * inv
__global__ __launch_bounds__(256) void norm_kernel(const float* __restrict__ sc,
                                                   const int* __restrict__ dst,
                                                   const ushort* __restrict__ rel,
                                                   const int* __restrict__ off,
                                                   float* __restrict__ out,
                                                   const float* __restrict__ mmf, int E) {
    float mn = mmf[0];
    float mx = mmf[1];
    float inv = 1.0f / (mx - mn);
    int i = blockIdx.x * 256 + threadIdx.x;
    if (i < E) {
        int p = off[dst[i]] + (int)rel[i];
        out[i] = (sc[p] - mn) * inv;
    }
}

extern "C" void kernel_launch(void* const* d_in, const int* in_sizes, int n_in,
                              void* d_out, int out_size, void* d_ws, size_t ws_size,
                              hipStream_t stream) {
    const float* x   = (const float*)d_in[0];
    const int*   src = (const int*)d_in[1];
    const int*   dst = (const int*)d_in[2];
    const float* Ws1 = (const float*)d_in[3];
    const float* Wn1 = (const float*)d_in[4];
    const float* b1  = (const float*)d_in[5];
    const float* Ws2 = (const float*)d_in[6];
    const float* Wn2 = (const float*)d_in[7];
    const float* b2  = (const float*)d_in[8];

    int N = in_sizes[0] / F;   // 100000
    int E = in_sizes[1];       // 1600000
    float* out = (float*)d_out;

    int nbN = (N + 255) / 256;
    int nbE = (E + 255) / 256;
    int nbEdgeBlocks = (N + 3) / 4;       // 25000
    int NF4 = N * F / 4;

    // workspace layout (4-byte elements)
    int* off  = (int*)d_ws;                  // N
    int* cnt  = off + N;                     // N
    int* srcS = cnt + N;                     // E
    ushort* rel = (ushort*)(srcS + E);       // E ushorts = E/2 words
    float* sc = (float*)((int*)rel + E / 2); // E
    int* bsum = (int*)(sc + E);              // 1024
    float* rdeg = (float*)(bsum + 1024);     // N
    float* mmf = (float*)(rdeg + N);         // 2 (+2 pad)
    float2* pmm = (float2*)(mmf + 4);        // 25600 float2
    uint* Wtb = (uint*)(pmm + 25600);        // 32768 uints (frag-major)
    size_t elemOff = 3 * (size_t)N + 2 * (size_t)E + (size_t)E / 2 + 1024 + 4 + 51200 + 32768;
    elemOff = (elemOff + 3) & ~(size_t)3;    // 16B align
    uint* xb   = (uint*)d_ws + elemOff;      // N*64
    uint* msgb = xb + (size_t)N * 64;        // N*64
    uint* h1b  = msgb + (size_t)N * 64;      // N*64
    uint* h2b  = h1b + (size_t)N * 64;       // N*64

    // init
    hipMemsetAsync(cnt, 0, (size_t)N * sizeof(int), stream);

    // CSR build (by dst): one atomic pass + scan + atomic-free fill
    rank_kernel<<<nbE, 256, 0, stream>>>(dst, cnt, rel, E);
    scan_block<<<nbN, 256, 0, stream>>>(cnt, off, bsum, N);
    scan_sums<<<1, 512, 0, stream>>>(bsum, nbN);
    scan_add_rdeg<<<nbN, 256, 0, stream>>>(off, bsum, cnt, rdeg, N);
    fill_kernel<<<nbE, 256, 0, stream>>>(src, dst, off, rel, srcS, E);

    // fused weights (frag-major) + input cast
    prep_kernel<<<(NF4 + 4 * 16384 + 255) / 256, 256, 0, stream>>>(
        x, Ws1, Wn1, Ws2, Wn2, xb, (ushort*)Wtb, NF4);

    int nbAggH = 2 * ((N + 3) / 4);   // XCD-parity half-row split

    // layer 1
    agg_gather_h<<<nbAggH, 256, 0, stream>>>(xb, off, srcS, rdeg, msgb, N, E);
    sage_mfma<<<(N + 63) / 64, 256, 0, stream>>>(xb, msgb, Wtb, b1, (ushort*)h1b, N);

    // layer 2
    agg_gather_h<<<nbAggH, 256, 0, stream>>>(h1b, off, srcS, rdeg, msgb, N, E);
    sage_mfma<<<(N + 63) / 64, 256, 0, stream>>>(h1b, msgb, Wtb + 16384, b2, (ushort*)h2b, N);

    // edge scores: two half-feature passes (footprint 12.8 MB each) + reduce + normalize
    edge_score_h<0><<<nbEdgeBlocks, 256, 0, stream>>>(h2b, off, srcS, sc, pmm, N, E);
    edge_score_h<1><<<nbEdgeBlocks, 256, 0, stream>>>(h2b, off, srcS, sc, pmm, N, E);
    minmax_final<<<1, 1024, 0, stream>>>(pmm, mmf, nbEdgeBlocks);
    norm_kernel<<<(E + 255) / 256, 256, 0, stream>>>(sc, dst, rel, off, out, mmf, E);
}